// Round 1
// baseline (589.244 us; speedup 1.0000x reference)
//
#include <hip/hip_runtime.h>
#include <cstddef>

// ---------------- workspace layout (float offsets) ----------------
#define WS_P0     0u         /* 4096x256, later reused for dots 1024x1024 */
#define WS_DOTS   0u
#define WS_HN0    1048576u   /* 4096x256, later reused for hc 6144x128 */
#define WS_HC     1048576u
#define WS_H1     2097152u   /* 4096x128 */
#define WS_H1N    2621440u   /* 4096x128 */
#define WS_P1     3145728u   /* 4096x128 */
#define WS_HN1    3670016u   /* 4096x128 */
#define WS_H2     4194304u   /* 4096x128 */
#define WS_X      4718592u   /* 6144x128 */
#define WS_OUTM   5505024u   /* 6144x128 */
#define WS_NEIGH  6291456u   /* 6144x128 */
#define WS_SQN    7077888u   /* 1024 */
#define WS_ROWSUM 7078912u   /* 6144 */
#define WS_SCAL   7085056u   /* 8: s0, s1, edge_cnt */
#define WS_INTS   7085568u   /* int area base */
// int offsets from WS_INTS
#define IO_NN     0          /* 1024 */
#define IO_DEG    1024       /* 4096 */
#define IO_CUR    5120       /* 4096 */
#define IO_ROWPTR 9216       /* 4097 */
#define IO_EIDX   13568      /* 69632 */

// ---------------- generic NT GEMM: C = act(A@B^T (+ A2@B2^T) + bias) -------
// grid = (N/64, M/64), block = 256. M,N,K multiples of 64/64/16.
__global__ __launch_bounds__(256, 2) void gemm_nt(
    const float* __restrict__ A, int lda,
    const float* __restrict__ B, int ldb,
    const float* __restrict__ A2, int lda2,
    const float* __restrict__ B2, int ldb2,
    const float* __restrict__ bias,
    float* __restrict__ C, int ldc,
    int K, int relu)
{
  __shared__ float As[16][68];
  __shared__ float Bs[16][68];
  const int tid = threadIdx.x;
  const int tx = tid & 15, ty = tid >> 4;
  const int lr = tid >> 2;
  const int lk = (tid & 3) << 2;
  const int i0 = blockIdx.y << 6;
  const int j0 = blockIdx.x << 6;
  float acc[4][4] = {};
  const int npass = (A2 != nullptr) ? 2 : 1;
  for (int pass = 0; pass < npass; ++pass) {
    const float* Ap = pass ? A2 : A; const int la = pass ? lda2 : lda;
    const float* Bp = pass ? B2 : B; const int lb = pass ? ldb2 : ldb;
    for (int k0 = 0; k0 < K; k0 += 16) {
      const float4 ag = *(const float4*)(Ap + (size_t)(i0 + lr) * la + (k0 + lk));
      const float4 bg = *(const float4*)(Bp + (size_t)(j0 + lr) * lb + (k0 + lk));
      __syncthreads();
      As[lk+0][lr]=ag.x; As[lk+1][lr]=ag.y; As[lk+2][lr]=ag.z; As[lk+3][lr]=ag.w;
      Bs[lk+0][lr]=bg.x; Bs[lk+1][lr]=bg.y; Bs[lk+2][lr]=bg.z; Bs[lk+3][lr]=bg.w;
      __syncthreads();
#pragma unroll
      for (int k = 0; k < 16; ++k) {
        const float4 a4 = *(const float4*)&As[k][ty << 2];
        const float4 b4 = *(const float4*)&Bs[k][tx << 2];
        const float aa[4] = {a4.x, a4.y, a4.z, a4.w};
        const float bb[4] = {b4.x, b4.y, b4.z, b4.w};
#pragma unroll
        for (int ii = 0; ii < 4; ++ii)
#pragma unroll
          for (int jj = 0; jj < 4; ++jj)
            acc[ii][jj] += aa[ii] * bb[jj];
      }
    }
  }
  float badd[4] = {0.f, 0.f, 0.f, 0.f};
  if (bias) {
    const float4 t = *(const float4*)(bias + j0 + (tx << 2));
    badd[0]=t.x; badd[1]=t.y; badd[2]=t.z; badd[3]=t.w;
  }
#pragma unroll
  for (int ii = 0; ii < 4; ++ii) {
    float4 o;
    o.x = acc[ii][0] + badd[0];
    o.y = acc[ii][1] + badd[1];
    o.z = acc[ii][2] + badd[2];
    o.w = acc[ii][3] + badd[3];
    if (relu) { o.x=fmaxf(o.x,0.f); o.y=fmaxf(o.y,0.f); o.z=fmaxf(o.z,0.f); o.w=fmaxf(o.w,0.f); }
    *(float4*)(C + (size_t)(i0 + (ty<<2) + ii) * ldc + j0 + (tx<<2)) = o;
  }
}

// ---------------- CSR build (bucket edges by dst) ----------------
__global__ void count_k(const int* __restrict__ dst, int* __restrict__ deg, int E) {
  const int e = blockIdx.x * 256 + threadIdx.x;
  if (e < E) atomicAdd(&deg[dst[e]], 1);
}

__global__ __launch_bounds__(1024) void scan_k(const int* __restrict__ deg,
                                               int* __restrict__ rowptr,
                                               int* __restrict__ cursor) {
  __shared__ int sums[1024];
  const int t = threadIdx.x;
  const int4 d = *(const int4*)(deg + (t << 2));
  const int local = d.x + d.y + d.z + d.w;
  sums[t] = local;
  __syncthreads();
  for (int off = 1; off < 1024; off <<= 1) {
    int v = (t >= off) ? sums[t - off] : 0;
    __syncthreads();
    sums[t] += v;
    __syncthreads();
  }
  const int excl = sums[t] - local;
  const int o0 = excl, o1 = o0 + d.x, o2 = o1 + d.y, o3 = o2 + d.z;
  rowptr[(t<<2)+0]=o0; rowptr[(t<<2)+1]=o1; rowptr[(t<<2)+2]=o2; rowptr[(t<<2)+3]=o3;
  cursor[(t<<2)+0]=o0; cursor[(t<<2)+1]=o1; cursor[(t<<2)+2]=o2; cursor[(t<<2)+3]=o3;
  if (t == 1023) rowptr[4096] = sums[1023];
}

__global__ void fill_k(const int* __restrict__ src, const int* __restrict__ dst,
                       int* __restrict__ cursor, int* __restrict__ eidx, int E) {
  const int e = blockIdx.x * 256 + threadIdx.x;
  if (e < E) {
    const int p = atomicAdd(&cursor[dst[e]], 1);
    eidx[p] = src[e];
  }
}

// segment_max as CSR gather. p >= 0 (relu'd) and every segment non-empty
// (self-loops), so init 0 reproduces the isfinite->0 semantics exactly.
__global__ void segmax_k(const float* __restrict__ p, const int* __restrict__ rowptr,
                         const int* __restrict__ eidx, float* __restrict__ hn, int F) {
  const int row = blockIdx.x, f = threadIdx.x;  // blockDim == F
  const int b = rowptr[row], e = rowptr[row + 1];
  float m = 0.f;
  for (int k = b; k < e; ++k) m = fmaxf(m, p[(size_t)eidx[k] * F + f]);
  hn[(size_t)row * F + f] = m;
}

// ---------------- small fused elementwise / reductions ----------------
__device__ inline float wave_sum(float v) {
#pragma unroll
  for (int o = 32; o > 0; o >>= 1) v += __shfl_down(v, o, 64);
  return v;
}

__global__ void relu_l2norm_k(const float* __restrict__ in, float* __restrict__ out) {
  const int row = blockIdx.x, f = threadIdx.x;  // 128 threads
  const float v = fmaxf(in[(size_t)row * 128 + f], 0.f);
  const float ss = wave_sum(v * v);
  __shared__ float w[2];
  if ((f & 63) == 0) w[f >> 6] = ss;
  __syncthreads();
  const float denom = fmaxf(sqrtf(w[0] + w[1]), 1e-12f);
  out[(size_t)row * 128 + f] = v / denom;
}

__global__ void sqn_k(const float* __restrict__ h2, float* __restrict__ sqn) {
  const int row = blockIdx.x, f = threadIdx.x;  // 128 threads
  const float v = h2[(size_t)row * 128 + f];
  const float ss = wave_sum(v * v);
  __shared__ float w[2];
  if ((f & 63) == 0) w[f >> 6] = ss;
  __syncthreads();
  if (f == 0) sqn[row] = w[0] + w[1];
}

// nearest neighbor (excluding self), tie-break smallest index = stable argsort pos 1
__global__ void argmin_k(const float* __restrict__ dots, const float* __restrict__ sqn,
                         int* __restrict__ nn) {
  const int i = blockIdx.x, tid = threadIdx.x;  // 256 threads
  float best = 3.402823466e38f; int bidx = 0x7fffffff;
  const float si = sqn[i];
  for (int j = tid; j < 1024; j += 256) {
    if (j == i) continue;
    float d2 = si + sqn[j] - 2.f * dots[(size_t)i * 1024 + j];
    d2 = fmaxf(d2, 0.f);
    if (d2 < best || (d2 == best && j < bidx)) { best = d2; bidx = j; }
  }
  __shared__ float bv[256]; __shared__ int bi[256];
  bv[tid] = best; bi[tid] = bidx;
  __syncthreads();
  for (int s = 128; s > 0; s >>= 1) {
    if (tid < s) {
      if (bv[tid+s] < bv[tid] || (bv[tid+s] == bv[tid] && bi[tid+s] < bi[tid])) {
        bv[tid] = bv[tid+s]; bi[tid] = bi[tid+s];
      }
    }
    __syncthreads();
  }
  if (tid == 0) nn[i] = bi[0];
}

__global__ void build_x_k(const float* __restrict__ h2, const int* __restrict__ nn,
                          const float* __restrict__ gaps, float* __restrict__ x) {
  const int row = blockIdx.x, f = threadIdx.x;  // 128 threads, grid 6144
  if (row < 4096) {
    x[(size_t)row * 128 + f] = h2[(size_t)row * 128 + f];
  } else {
    const int s = row - 4096, i = s >> 1, r = s & 1;
    const float g = gaps[(i << 1) + r];
    const float c  = h2[(size_t)i * 128 + f];
    const float cn = h2[(size_t)nn[i] * 128 + f];
    x[(size_t)row * 128 + f] = c + g * (cn - c);
  }
}

// ---------------- fused: sigmoid(out@out^T) -> loss + threshold @ x ----------
// grid = (96, JC), block 256. Each block owns 64 i-rows, a j-chunk of njt tiles.
__global__ __launch_bounds__(256, 2) void fused_big(
    const float* __restrict__ outm,   // 6144x128
    const float* __restrict__ x,      // 6144x128
    const float* __restrict__ adj,    // 4096x4096
    float* __restrict__ neigh,        // 6144x128, pre-zeroed
    float* __restrict__ rowsum,       // 6144, pre-zeroed
    float* __restrict__ scal,         // [s0,s1,edge_cnt], pre-zeroed
    int njt)
{
  __shared__ float As[16][68];
  __shared__ float Bs[16][68];
  __shared__ float St[64][68];      // thresholded S, transposed: St[j_local][i_local]
  __shared__ float rsum_l[64];
  __shared__ float red[256];

  const int tid = threadIdx.x;
  const int tx = tid & 15, ty = tid >> 4;
  const int lr = tid >> 2, lk = (tid & 3) << 2;
  const int ntx = tid & 31, nty = tid >> 5;
  const int i0 = blockIdx.x << 6;
  const int jt0 = blockIdx.y * njt;

  float nacc[8][4] = {};
  float rs[4] = {0.f, 0.f, 0.f, 0.f};
  float s0 = 0.f, s1 = 0.f, cnt = 0.f;
  if (tid < 64) rsum_l[tid] = 0.f;

  for (int jt = 0; jt < njt; ++jt) {
    const int j0 = (jt0 + jt) << 6;
    float acc[4][4] = {};
    for (int k0 = 0; k0 < 128; k0 += 16) {
      const float4 ag = *(const float4*)(outm + (size_t)(i0 + lr) * 128 + (k0 + lk));
      const float4 bg = *(const float4*)(outm + (size_t)(j0 + lr) * 128 + (k0 + lk));
      __syncthreads();
      As[lk+0][lr]=ag.x; As[lk+1][lr]=ag.y; As[lk+2][lr]=ag.z; As[lk+3][lr]=ag.w;
      Bs[lk+0][lr]=bg.x; Bs[lk+1][lr]=bg.y; Bs[lk+2][lr]=bg.z; Bs[lk+3][lr]=bg.w;
      __syncthreads();
#pragma unroll
      for (int k = 0; k < 16; ++k) {
        const float4 a4 = *(const float4*)&As[k][ty << 2];
        const float4 b4 = *(const float4*)&Bs[k][tx << 2];
        const float aa[4] = {a4.x, a4.y, a4.z, a4.w};
        const float bb[4] = {b4.x, b4.y, b4.z, b4.w};
#pragma unroll
        for (int ii = 0; ii < 4; ++ii)
#pragma unroll
          for (int jj = 0; jj < 4; ++jj)
            acc[ii][jj] += aa[ii] * bb[jj];
      }
    }
    // epilogue: sigmoid, weighted-loss partials, edge count, threshold -> St
    const bool adj_i = (i0 < 4096) && (j0 < 4096);
#pragma unroll
    for (int ii = 0; ii < 4; ++ii) {
      const int gi = i0 + (ty << 2) + ii;
      float a_[4] = {0.f, 0.f, 0.f, 0.f};
      if (adj_i) {
        const float4 av = *(const float4*)(adj + (size_t)gi * 4096 + j0 + (tx << 2));
        a_[0]=av.x; a_[1]=av.y; a_[2]=av.z; a_[3]=av.w;
      }
#pragma unroll
      for (int jj = 0; jj < 4; ++jj) {
        const float sg = 1.f / (1.f + __expf(-acc[ii][jj]));
        if (adj_i) {
          const float d = sg - a_[jj];
          if (a_[jj] != 0.f) { s1 += d * d; cnt += 1.f; }
          else               { s0 += d * d; }
        }
        const float t = (sg >= 0.5f) ? sg : 0.f;
        rs[ii] += t;
        St[(tx << 2) + jj][(ty << 2) + ii] = t;
      }
    }
    __syncthreads();
    // neigh partial: nacc(i_local, c) += sum_j St[j][i_local] * x[j0+j][c]
    const float* xp = x + (size_t)j0 * 128 + (ntx << 2);
#pragma unroll 4
    for (int j2 = 0; j2 < 64; ++j2) {
      const float4 xv = *(const float4*)(xp + (size_t)j2 * 128);
      const float4 sa = *(const float4*)&St[j2][nty << 3];
      const float4 sb = *(const float4*)&St[j2][(nty << 3) + 4];
      const float sv[8] = {sa.x, sa.y, sa.z, sa.w, sb.x, sb.y, sb.z, sb.w};
      const float xa[4] = {xv.x, xv.y, xv.z, xv.w};
#pragma unroll
      for (int r = 0; r < 8; ++r)
#pragma unroll
        for (int c = 0; c < 4; ++c)
          nacc[r][c] += sv[r] * xa[c];
    }
    __syncthreads();
  }
  // flush neigh partials (one add per element; 8-way contention across j-chunks)
#pragma unroll
  for (int r = 0; r < 8; ++r) {
    const int gi = i0 + (nty << 3) + r;
#pragma unroll
    for (int c = 0; c < 4; ++c)
      atomicAdd(&neigh[(size_t)gi * 128 + (ntx << 2) + c], nacc[r][c]);
  }
  // rowsum
#pragma unroll
  for (int ii = 0; ii < 4; ++ii)
    atomicAdd(&rsum_l[(ty << 2) + ii], rs[ii]);
  __syncthreads();
  if (tid < 64) atomicAdd(&rowsum[i0 + tid], rsum_l[tid]);
  // loss & edge-count block reduction
  red[tid] = s0; __syncthreads();
  for (int s = 128; s > 0; s >>= 1) { if (tid < s) red[tid] += red[tid + s]; __syncthreads(); }
  if (tid == 0) atomicAdd(&scal[0], red[0]);
  __syncthreads();
  red[tid] = s1; __syncthreads();
  for (int s = 128; s > 0; s >>= 1) { if (tid < s) red[tid] += red[tid + s]; __syncthreads(); }
  if (tid == 0) atomicAdd(&scal[1], red[0]);
  __syncthreads();
  red[tid] = cnt; __syncthreads();
  for (int s = 128; s > 0; s >>= 1) { if (tid < s) red[tid] += red[tid + s]; __syncthreads(); }
  if (tid == 0) atomicAdd(&scal[2], red[0]);
}

__global__ void neigh_div_k(float* __restrict__ neigh, const float* __restrict__ rowsum) {
  const int row = blockIdx.x, f = threadIdx.x;
  neigh[(size_t)row * 128 + f] /= (rowsum[row] + 1.f);
}

__global__ void logits_k(const float* __restrict__ hc, const float* __restrict__ Wclf,
                         const float* __restrict__ bclf, float* __restrict__ outp) {
  const int i = blockIdx.x, f = threadIdx.x;  // 128 threads
  const float h = hc[(size_t)i * 128 + f];
  const float v0 = wave_sum(h * Wclf[f]);
  const float v1 = wave_sum(h * Wclf[128 + f]);
  __shared__ float w0[2], w1[2];
  if ((f & 63) == 0) { w0[f >> 6] = v0; w1[f >> 6] = v1; }
  __syncthreads();
  if (f == 0) {
    outp[(size_t)i * 2 + 0] = w0[0] + w0[1] + bclf[0];
    outp[(size_t)i * 2 + 1] = w1[0] + w1[1] + bclf[1];
  }
}

__global__ void y_k(const int* __restrict__ labels, float* __restrict__ outp) {
  const int i = blockIdx.x * 256 + threadIdx.x;
  if (i < 6144) outp[i] = (i < 4096) ? (float)labels[i] : 1.f;
}

__global__ void loss_fin_k(const float* __restrict__ scal, float* __restrict__ outp) {
  const float cnt = scal[2];
  const float neg_w = cnt / (16777216.f - cnt);
  outp[0] = neg_w * scal[0] + scal[1];
}

// ---------------- launcher ----------------
extern "C" void kernel_launch(void* const* d_in, const int* in_sizes, int n_in,
                              void* d_out, int out_size, void* d_ws, size_t ws_size,
                              hipStream_t stream) {
  const float* feat     = (const float*)d_in[0];
  const float* adj      = (const float*)d_in[1];
  const int*   src      = (const int*)d_in[2];
  const int*   dst      = (const int*)d_in[3];
  const int*   labels   = (const int*)d_in[4];
  const float* W_pool0  = (const float*)d_in[5];
  const float* b_pool0  = (const float*)d_in[6];
  const float* W_self0  = (const float*)d_in[7];
  const float* W_neigh0 = (const float*)d_in[8];
  const float* b0       = (const float*)d_in[9];
  const float* W_pool1  = (const float*)d_in[10];
  const float* b_pool1  = (const float*)d_in[11];
  const float* W_self1  = (const float*)d_in[12];
  const float* W_neigh1 = (const float*)d_in[13];
  const float* b1       = (const float*)d_in[14];
  const float* de_w     = (const float*)d_in[15];
  const float* W_conv   = (const float*)d_in[16];
  const float* W_clf    = (const float*)d_in[17];
  const float* b_clf    = (const float*)d_in[18];
  const float* gaps     = (const float*)d_in[19];
  const int E = in_sizes[2];  // 69632 (E + self-loops)

  float* ws = (float*)d_ws;
  float* p0     = ws + WS_P0;
  float* dots   = ws + WS_DOTS;
  float* hn0    = ws + WS_HN0;
  float* hc     = ws + WS_HC;
  float* h1     = ws + WS_H1;
  float* h1n    = ws + WS_H1N;
  float* p1     = ws + WS_P1;
  float* hn1    = ws + WS_HN1;
  float* h2     = ws + WS_H2;
  float* x      = ws + WS_X;
  float* outm   = ws + WS_OUTM;
  float* neigh  = ws + WS_NEIGH;
  float* sqn    = ws + WS_SQN;
  float* rowsum = ws + WS_ROWSUM;
  float* scal   = ws + WS_SCAL;
  int* ibase    = (int*)(ws + WS_INTS);
  int* nn       = ibase + IO_NN;
  int* deg      = ibase + IO_DEG;
  int* cursor   = ibase + IO_CUR;
  int* rowptr   = ibase + IO_ROWPTR;
  int* eidx     = ibase + IO_EIDX;

  float* outp = (float*)d_out;
  const dim3 blk(256);

  // zero-init accumulators (ws is poisoned 0xAA before every call)
  hipMemsetAsync(deg, 0, 4096 * sizeof(int), stream);
  hipMemsetAsync(neigh, 0, 786432 * sizeof(float), stream);
  hipMemsetAsync(rowsum, 0, (6144 + 8) * sizeof(float), stream);  // rowsum + scal

  // CSR bucket-by-dst
  count_k<<<(E + 255) / 256, blk, 0, stream>>>(dst, deg, E);
  scan_k<<<1, 1024, 0, stream>>>(deg, rowptr, cursor);
  fill_k<<<(E + 255) / 256, blk, 0, stream>>>(src, dst, cursor, eidx, E);

  // layer 0
  gemm_nt<<<dim3(4, 64), blk, 0, stream>>>(feat, 256, W_pool0, 256,
                                           nullptr, 0, nullptr, 0,
                                           b_pool0, p0, 256, 256, 1);
  segmax_k<<<4096, 256, 0, stream>>>(p0, rowptr, eidx, hn0, 256);
  gemm_nt<<<dim3(2, 64), blk, 0, stream>>>(feat, 256, W_self0, 256,
                                           hn0, 256, W_neigh0, 256,
                                           b0, h1, 128, 256, 0);
  relu_l2norm_k<<<4096, 128, 0, stream>>>(h1, h1n);

  // layer 1
  gemm_nt<<<dim3(2, 64), blk, 0, stream>>>(h1n, 128, W_pool1, 128,
                                           nullptr, 0, nullptr, 0,
                                           b_pool1, p1, 128, 128, 1);
  segmax_k<<<4096, 128, 0, stream>>>(p1, rowptr, eidx, hn1, 128);
  gemm_nt<<<dim3(2, 64), blk, 0, stream>>>(h1n, 128, W_self1, 128,
                                           hn1, 128, W_neigh1, 128,
                                           b1, h2, 128, 128, 0);

  // SMOTE
  gemm_nt<<<dim3(16, 16), blk, 0, stream>>>(h2, 128, h2, 128,
                                            nullptr, 0, nullptr, 0,
                                            nullptr, dots, 1024, 128, 0);
  sqn_k<<<1024, 128, 0, stream>>>(h2, sqn);
  argmin_k<<<1024, 256, 0, stream>>>(dots, sqn, nn);
  build_x_k<<<6144, 128, 0, stream>>>(h2, nn, gaps, x);

  // decoder + fused adjacency pass
  gemm_nt<<<dim3(2, 96), blk, 0, stream>>>(x, 128, de_w, 128,
                                           nullptr, 0, nullptr, 0,
                                           nullptr, outm, 128, 128, 0);
  fused_big<<<dim3(96, 8), blk, 0, stream>>>(outm, x, adj, neigh, rowsum, scal, 12);
  neigh_div_k<<<6144, 128, 0, stream>>>(neigh, rowsum);

  // classifier
  gemm_nt<<<dim3(2, 96), blk, 0, stream>>>(x, 128, W_conv, 256,
                                           neigh, 128, W_conv + 128, 256,
                                           nullptr, hc, 128, 128, 0);
  logits_k<<<6144, 128, 0, stream>>>(hc, W_clf, b_clf, outp);
  y_k<<<24, blk, 0, stream>>>(labels, outp + 12288);
  loss_fin_k<<<1, 1, 0, stream>>>(scal, outp + 18432);

  (void)n_in; (void)out_size; (void)ws_size; (void)in_sizes;
}

// Round 2
// 476.167 us; speedup vs baseline: 1.2375x; 1.2375x over previous
//
#include <hip/hip_runtime.h>
#include <cstddef>

typedef unsigned short ushort_t;
typedef __attribute__((ext_vector_type(8))) short bf16x8;
typedef __attribute__((ext_vector_type(4))) float f32x4;

// ---------------- workspace layout (float offsets) ----------------
#define WS_P0     0u         /* 4096x256, later reused for dots 1024x1024 */
#define WS_DOTS   0u
#define WS_HN0    1048576u   /* 4096x256, later reused for hc 6144x128 */
#define WS_HC     1048576u
#define WS_H1     2097152u   /* 4096x128; dead after relu_l2norm -> reused for ob (bf16 6144x128) */
#define WS_H1N    2621440u   /* 4096x128 */
#define WS_P1     3145728u   /* 4096x128; dead after segmax1 -> reused for xt (bf16 128x6144) */
#define WS_HN1    3670016u   /* 4096x128 */
#define WS_H2     4194304u   /* 4096x128 */
#define WS_X      4718592u   /* 6144x128 */
#define WS_OUTM   5505024u   /* 6144x128 */
#define WS_NEIGH  6291456u   /* 6144x128 */
#define WS_SQN    7077888u   /* 1024 */
#define WS_ROWSUM 7078912u   /* 6144 */
#define WS_SCAL   7085056u   /* 8: s0, s1, edge_cnt */
#define WS_INTS   7085568u   /* int area base */
// int offsets from WS_INTS
#define IO_NN     0          /* 1024 */
#define IO_DEG    1024       /* 4096 */
#define IO_CUR    5120       /* 4096 */
#define IO_ROWPTR 9216       /* 4097 */
#define IO_EIDX   13568      /* 69632 */

__device__ inline ushort_t f2bf(float f) {
  unsigned u = __float_as_uint(f);
  u += 0x7fff + ((u >> 16) & 1);   // round-to-nearest-even
  return (ushort_t)(u >> 16);
}

// ---------------- generic NT GEMM: C = act(A@B^T (+ A2@B2^T) + bias) -------
// grid = (N/64, M/64), block = 256. M,N,K multiples of 64/64/16.
__global__ __launch_bounds__(256, 2) void gemm_nt(
    const float* __restrict__ A, int lda,
    const float* __restrict__ B, int ldb,
    const float* __restrict__ A2, int lda2,
    const float* __restrict__ B2, int ldb2,
    const float* __restrict__ bias,
    float* __restrict__ C, int ldc,
    int K, int relu)
{
  __shared__ float As[16][68];
  __shared__ float Bs[16][68];
  const int tid = threadIdx.x;
  const int tx = tid & 15, ty = tid >> 4;
  const int lr = tid >> 2;
  const int lk = (tid & 3) << 2;
  const int i0 = blockIdx.y << 6;
  const int j0 = blockIdx.x << 6;
  float acc[4][4] = {};
  const int npass = (A2 != nullptr) ? 2 : 1;
  for (int pass = 0; pass < npass; ++pass) {
    const float* Ap = pass ? A2 : A; const int la = pass ? lda2 : lda;
    const float* Bp = pass ? B2 : B; const int lb = pass ? ldb2 : ldb;
    for (int k0 = 0; k0 < K; k0 += 16) {
      const float4 ag = *(const float4*)(Ap + (size_t)(i0 + lr) * la + (k0 + lk));
      const float4 bg = *(const float4*)(Bp + (size_t)(j0 + lr) * lb + (k0 + lk));
      __syncthreads();
      As[lk+0][lr]=ag.x; As[lk+1][lr]=ag.y; As[lk+2][lr]=ag.z; As[lk+3][lr]=ag.w;
      Bs[lk+0][lr]=bg.x; Bs[lk+1][lr]=bg.y; Bs[lk+2][lr]=bg.z; Bs[lk+3][lr]=bg.w;
      __syncthreads();
#pragma unroll
      for (int k = 0; k < 16; ++k) {
        const float4 a4 = *(const float4*)&As[k][ty << 2];
        const float4 b4 = *(const float4*)&Bs[k][tx << 2];
        const float aa[4] = {a4.x, a4.y, a4.z, a4.w};
        const float bb[4] = {b4.x, b4.y, b4.z, b4.w};
#pragma unroll
        for (int ii = 0; ii < 4; ++ii)
#pragma unroll
          for (int jj = 0; jj < 4; ++jj)
            acc[ii][jj] += aa[ii] * bb[jj];
      }
    }
  }
  float badd[4] = {0.f, 0.f, 0.f, 0.f};
  if (bias) {
    const float4 t = *(const float4*)(bias + j0 + (tx << 2));
    badd[0]=t.x; badd[1]=t.y; badd[2]=t.z; badd[3]=t.w;
  }
#pragma unroll
  for (int ii = 0; ii < 4; ++ii) {
    float4 o;
    o.x = acc[ii][0] + badd[0];
    o.y = acc[ii][1] + badd[1];
    o.z = acc[ii][2] + badd[2];
    o.w = acc[ii][3] + badd[3];
    if (relu) { o.x=fmaxf(o.x,0.f); o.y=fmaxf(o.y,0.f); o.z=fmaxf(o.z,0.f); o.w=fmaxf(o.w,0.f); }
    *(float4*)(C + (size_t)(i0 + (ty<<2) + ii) * ldc + j0 + (tx<<2)) = o;
  }
}

// ---------------- CSR build (bucket edges by dst) ----------------
__global__ void count_k(const int* __restrict__ dst, int* __restrict__ deg, int E) {
  const int e = blockIdx.x * 256 + threadIdx.x;
  if (e < E) atomicAdd(&deg[dst[e]], 1);
}

__global__ __launch_bounds__(1024) void scan_k(const int* __restrict__ deg,
                                               int* __restrict__ rowptr,
                                               int* __restrict__ cursor) {
  __shared__ int sums[1024];
  const int t = threadIdx.x;
  const int4 d = *(const int4*)(deg + (t << 2));
  const int local = d.x + d.y + d.z + d.w;
  sums[t] = local;
  __syncthreads();
  for (int off = 1; off < 1024; off <<= 1) {
    int v = (t >= off) ? sums[t - off] : 0;
    __syncthreads();
    sums[t] += v;
    __syncthreads();
  }
  const int excl = sums[t] - local;
  const int o0 = excl, o1 = o0 + d.x, o2 = o1 + d.y, o3 = o2 + d.z;
  rowptr[(t<<2)+0]=o0; rowptr[(t<<2)+1]=o1; rowptr[(t<<2)+2]=o2; rowptr[(t<<2)+3]=o3;
  cursor[(t<<2)+0]=o0; cursor[(t<<2)+1]=o1; cursor[(t<<2)+2]=o2; cursor[(t<<2)+3]=o3;
  if (t == 1023) rowptr[4096] = sums[1023];
}

__global__ void fill_k(const int* __restrict__ src, const int* __restrict__ dst,
                       int* __restrict__ cursor, int* __restrict__ eidx, int E) {
  const int e = blockIdx.x * 256 + threadIdx.x;
  if (e < E) {
    const int p = atomicAdd(&cursor[dst[e]], 1);
    eidx[p] = src[e];
  }
}

// segment_max as CSR gather. p >= 0 (relu'd) and every segment non-empty
// (self-loops), so init 0 reproduces the isfinite->0 semantics exactly.
__global__ void segmax_k(const float* __restrict__ p, const int* __restrict__ rowptr,
                         const int* __restrict__ eidx, float* __restrict__ hn, int F) {
  const int row = blockIdx.x, f = threadIdx.x;  // blockDim == F
  const int b = rowptr[row], e = rowptr[row + 1];
  float m = 0.f;
  for (int k = b; k < e; ++k) m = fmaxf(m, p[(size_t)eidx[k] * F + f]);
  hn[(size_t)row * F + f] = m;
}

// ---------------- small fused elementwise / reductions ----------------
__device__ inline float wave_sum(float v) {
#pragma unroll
  for (int o = 32; o > 0; o >>= 1) v += __shfl_down(v, o, 64);
  return v;
}

__global__ void relu_l2norm_k(const float* __restrict__ in, float* __restrict__ out) {
  const int row = blockIdx.x, f = threadIdx.x;  // 128 threads
  const float v = fmaxf(in[(size_t)row * 128 + f], 0.f);
  const float ss = wave_sum(v * v);
  __shared__ float w[2];
  if ((f & 63) == 0) w[f >> 6] = ss;
  __syncthreads();
  const float denom = fmaxf(sqrtf(w[0] + w[1]), 1e-12f);
  out[(size_t)row * 128 + f] = v / denom;
}

__global__ void sqn_k(const float* __restrict__ h2, float* __restrict__ sqn) {
  const int row = blockIdx.x, f = threadIdx.x;  // 128 threads
  const float v = h2[(size_t)row * 128 + f];
  const float ss = wave_sum(v * v);
  __shared__ float w[2];
  if ((f & 63) == 0) w[f >> 6] = ss;
  __syncthreads();
  if (f == 0) sqn[row] = w[0] + w[1];
}

// nearest neighbor (excluding self), tie-break smallest index = stable argsort pos 1
__global__ void argmin_k(const float* __restrict__ dots, const float* __restrict__ sqn,
                         int* __restrict__ nn) {
  const int i = blockIdx.x, tid = threadIdx.x;  // 256 threads
  float best = 3.402823466e38f; int bidx = 0x7fffffff;
  const float si = sqn[i];
  for (int j = tid; j < 1024; j += 256) {
    if (j == i) continue;
    float d2 = si + sqn[j] - 2.f * dots[(size_t)i * 1024 + j];
    d2 = fmaxf(d2, 0.f);
    if (d2 < best || (d2 == best && j < bidx)) { best = d2; bidx = j; }
  }
  __shared__ float bv[256]; __shared__ int bi[256];
  bv[tid] = best; bi[tid] = bidx;
  __syncthreads();
  for (int s = 128; s > 0; s >>= 1) {
    if (tid < s) {
      if (bv[tid+s] < bv[tid] || (bv[tid+s] == bv[tid] && bi[tid+s] < bi[tid])) {
        bv[tid] = bv[tid+s]; bi[tid] = bi[tid+s];
      }
    }
    __syncthreads();
  }
  if (tid == 0) nn[i] = bi[0];
}

__global__ void build_x_k(const float* __restrict__ h2, const int* __restrict__ nn,
                          const float* __restrict__ gaps, float* __restrict__ x) {
  const int row = blockIdx.x, f = threadIdx.x;  // 128 threads, grid 6144
  if (row < 4096) {
    x[(size_t)row * 128 + f] = h2[(size_t)row * 128 + f];
  } else {
    const int s = row - 4096, i = s >> 1, r = s & 1;
    const float g = gaps[(i << 1) + r];
    const float c  = h2[(size_t)i * 128 + f];
    const float cn = h2[(size_t)nn[i] * 128 + f];
    x[(size_t)row * 128 + f] = c + g * (cn - c);
  }
}

// ---------------- bf16 conversion helpers ----------------
__global__ void conv_ob_k(const float* __restrict__ in, ushort_t* __restrict__ out, int n) {
  const int i = blockIdx.x * 256 + threadIdx.x;
  if (i < n) out[i] = f2bf(in[i]);
}

// x (6144x128 f32) -> xt (128x6144 bf16), 64x64 LDS tile transpose
__global__ void conv_xt_k(const float* __restrict__ x, ushort_t* __restrict__ xt) {
  __shared__ ushort_t t[64][65];
  const int i0 = blockIdx.x << 6, c0 = blockIdx.y << 6;
  const int il = threadIdx.x & 63, rl = threadIdx.x >> 6;
#pragma unroll
  for (int rr = 0; rr < 16; ++rr) {
    const int r = (rr << 2) + rl;
    t[r][il] = f2bf(x[(size_t)(i0 + r) * 128 + c0 + il]);
  }
  __syncthreads();
#pragma unroll
  for (int rr = 0; rr < 16; ++rr) {
    const int c = (rr << 2) + rl;
    xt[(size_t)(c0 + c) * 6144 + i0 + il] = t[il][c];
  }
}

// ---------------- fused MFMA: sigmoid(out@out^T) -> loss + threshold @ x ----
// grid = (96, 8), block 256 (4 waves). Block owns 64 i-rows x njt 64-wide j-tiles.
// Wave w exclusively owns i-rows [w*16, w*16+16) incl. its P rows in LDS, so the
// j-loop runs with ZERO barriers (no barrier-drain stall).
__global__ __launch_bounds__(256, 4) void fused_mfma(
    const ushort_t* __restrict__ ob,   // 6144x128 bf16 (out)
    const ushort_t* __restrict__ xt,   // 128x6144 bf16 (x transposed)
    const float* __restrict__ adj,     // 4096x4096
    float* __restrict__ neigh,         // 6144x128, pre-zeroed
    float* __restrict__ rowsum,        // 6144, pre-zeroed
    float* __restrict__ scal,          // [s0,s1,edge_cnt], pre-zeroed
    int njt)
{
  __shared__ ushort_t P[64][72];       // row stride 144B -> 16B aligned b128 reads
  __shared__ float red[256];
  const int tid = threadIdx.x;
  const int w = tid >> 6, lane = tid & 63;
  const int lo = lane & 15, hi = lane >> 4;
  const int i0 = blockIdx.x << 6;
  const int iw = i0 + (w << 4);
  const int jt0 = blockIdx.y * njt;

  // A-fragments of out_i: register-resident across the whole j-loop
  bf16x8 ao[4];
  {
    const ushort_t* ap = ob + (size_t)(iw + lo) * 128 + (hi << 3);
#pragma unroll
    for (int kk = 0; kk < 4; ++kk) ao[kk] = *(const bf16x8*)(ap + (kk << 5));
  }
  f32x4 oacc[8];
#pragma unroll
  for (int s = 0; s < 8; ++s) oacc[s] = (f32x4){0.f, 0.f, 0.f, 0.f};
  float s0 = 0.f, s1 = 0.f, cnt = 0.f;
  float rs[4] = {0.f, 0.f, 0.f, 0.f};

  for (int jt = 0; jt < njt; ++jt) {
    const int j0 = (jt0 + jt) << 6;
    // ---- S = out_i @ out_j^T (16 MFMA / wave) ----
    f32x4 sacc[4];
#pragma unroll
    for (int c = 0; c < 4; ++c) sacc[c] = (f32x4){0.f, 0.f, 0.f, 0.f};
#pragma unroll
    for (int c = 0; c < 4; ++c) {
      const ushort_t* bp = ob + (size_t)(j0 + (c << 4) + lo) * 128 + (hi << 3);
#pragma unroll
      for (int kk = 0; kk < 4; ++kk) {
        const bf16x8 b = *(const bf16x8*)(bp + (kk << 5));
        sacc[c] = __builtin_amdgcn_mfma_f32_16x16x32_bf16(ao[kk], b, sacc[c], 0, 0, 0);
      }
    }
    // ---- epilogue: sigmoid, weighted loss partials, threshold -> P (LDS) ----
    const bool aj = (i0 < 4096) && (j0 < 4096);
#pragma unroll
    for (int c = 0; c < 4; ++c) {
      const int gj = j0 + (c << 4) + lo;
#pragma unroll
      for (int r = 0; r < 4; ++r) {
        const float sg = 1.f / (1.f + __expf(-sacc[c][r]));
        if (aj) {
          const float a = adj[(size_t)(iw + (hi << 2) + r) * 4096 + gj];
          const float d = sg - a;
          if (a != 0.f) { s1 += d * d; cnt += 1.f; }
          else          { s0 += d * d; }
        }
        const float t = (sg >= 0.5f) ? sg : 0.f;
        rs[r] += t;
        P[(w << 4) + (hi << 2) + r][(c << 4) + lo] = f2bf(t);
      }
    }
    // ---- neigh partial: oacc += P @ x_j (16 MFMA / wave), wave-private P ----
    const bf16x8 pa0 = *(const bf16x8*)&P[(w << 4) + lo][hi << 3];
    const bf16x8 pa1 = *(const bf16x8*)&P[(w << 4) + lo][32 + (hi << 3)];
#pragma unroll
    for (int s = 0; s < 8; ++s) {
      const ushort_t* xp = xt + (size_t)((s << 4) + lo) * 6144 + j0 + (hi << 3);
      const bf16x8 xb0 = *(const bf16x8*)xp;
      const bf16x8 xb1 = *(const bf16x8*)(xp + 32);
      oacc[s] = __builtin_amdgcn_mfma_f32_16x16x32_bf16(pa0, xb0, oacc[s], 0, 0, 0);
      oacc[s] = __builtin_amdgcn_mfma_f32_16x16x32_bf16(pa1, xb1, oacc[s], 0, 0, 0);
    }
  }
  // ---- rowsum: reduce rs over the 16 lanes of each quad-group ----
#pragma unroll
  for (int r = 0; r < 4; ++r) {
    float v = rs[r];
#pragma unroll
    for (int m = 1; m < 16; m <<= 1) v += __shfl_xor(v, m, 64);
    if (lo == 0) atomicAdd(&rowsum[iw + (hi << 2) + r], v);
  }
  // ---- neigh flush (8 j-chunks accumulate) ----
#pragma unroll
  for (int s = 0; s < 8; ++s)
#pragma unroll
    for (int r = 0; r < 4; ++r)
      atomicAdd(&neigh[(size_t)(iw + (hi << 2) + r) * 128 + (s << 4) + lo], oacc[s][r]);
  // ---- loss & edge-count block reductions ----
  red[tid] = s0; __syncthreads();
  for (int s = 128; s > 0; s >>= 1) { if (tid < s) red[tid] += red[tid + s]; __syncthreads(); }
  if (tid == 0) atomicAdd(&scal[0], red[0]);
  __syncthreads();
  red[tid] = s1; __syncthreads();
  for (int s = 128; s > 0; s >>= 1) { if (tid < s) red[tid] += red[tid + s]; __syncthreads(); }
  if (tid == 0) atomicAdd(&scal[1], red[0]);
  __syncthreads();
  red[tid] = cnt; __syncthreads();
  for (int s = 128; s > 0; s >>= 1) { if (tid < s) red[tid] += red[tid + s]; __syncthreads(); }
  if (tid == 0) atomicAdd(&scal[2], red[0]);
}

__global__ void neigh_div_k(float* __restrict__ neigh, const float* __restrict__ rowsum) {
  const int row = blockIdx.x, f = threadIdx.x;
  neigh[(size_t)row * 128 + f] /= (rowsum[row] + 1.f);
}

__global__ void logits_k(const float* __restrict__ hc, const float* __restrict__ Wclf,
                         const float* __restrict__ bclf, float* __restrict__ outp) {
  const int i = blockIdx.x, f = threadIdx.x;  // 128 threads
  const float h = hc[(size_t)i * 128 + f];
  const float v0 = wave_sum(h * Wclf[f]);
  const float v1 = wave_sum(h * Wclf[128 + f]);
  __shared__ float w0[2], w1[2];
  if ((f & 63) == 0) { w0[f >> 6] = v0; w1[f >> 6] = v1; }
  __syncthreads();
  if (f == 0) {
    outp[(size_t)i * 2 + 0] = w0[0] + w0[1] + bclf[0];
    outp[(size_t)i * 2 + 1] = w1[0] + w1[1] + bclf[1];
  }
}

__global__ void y_k(const int* __restrict__ labels, float* __restrict__ outp) {
  const int i = blockIdx.x * 256 + threadIdx.x;
  if (i < 6144) outp[i] = (i < 4096) ? (float)labels[i] : 1.f;
}

__global__ void loss_fin_k(const float* __restrict__ scal, float* __restrict__ outp) {
  const float cnt = scal[2];
  const float neg_w = cnt / (16777216.f - cnt);
  outp[0] = neg_w * scal[0] + scal[1];
}

// ---------------- launcher ----------------
extern "C" void kernel_launch(void* const* d_in, const int* in_sizes, int n_in,
                              void* d_out, int out_size, void* d_ws, size_t ws_size,
                              hipStream_t stream) {
  const float* feat     = (const float*)d_in[0];
  const float* adj      = (const float*)d_in[1];
  const int*   src      = (const int*)d_in[2];
  const int*   dst      = (const int*)d_in[3];
  const int*   labels   = (const int*)d_in[4];
  const float* W_pool0  = (const float*)d_in[5];
  const float* b_pool0  = (const float*)d_in[6];
  const float* W_self0  = (const float*)d_in[7];
  const float* W_neigh0 = (const float*)d_in[8];
  const float* b0       = (const float*)d_in[9];
  const float* W_pool1  = (const float*)d_in[10];
  const float* b_pool1  = (const float*)d_in[11];
  const float* W_self1  = (const float*)d_in[12];
  const float* W_neigh1 = (const float*)d_in[13];
  const float* b1       = (const float*)d_in[14];
  const float* de_w     = (const float*)d_in[15];
  const float* W_conv   = (const float*)d_in[16];
  const float* W_clf    = (const float*)d_in[17];
  const float* b_clf    = (const float*)d_in[18];
  const float* gaps     = (const float*)d_in[19];
  const int E = in_sizes[2];  // 69632 (E + self-loops)

  float* ws = (float*)d_ws;
  float* p0     = ws + WS_P0;
  float* dots   = ws + WS_DOTS;
  float* hn0    = ws + WS_HN0;
  float* hc     = ws + WS_HC;
  float* h1     = ws + WS_H1;
  float* h1n    = ws + WS_H1N;
  float* p1     = ws + WS_P1;
  float* hn1    = ws + WS_HN1;
  float* h2     = ws + WS_H2;
  float* x      = ws + WS_X;
  float* outm   = ws + WS_OUTM;
  float* neigh  = ws + WS_NEIGH;
  float* sqn    = ws + WS_SQN;
  float* rowsum = ws + WS_ROWSUM;
  float* scal   = ws + WS_SCAL;
  int* ibase    = (int*)(ws + WS_INTS);
  int* nn       = ibase + IO_NN;
  int* deg      = ibase + IO_DEG;
  int* cursor   = ibase + IO_CUR;
  int* rowptr   = ibase + IO_ROWPTR;
  int* eidx     = ibase + IO_EIDX;
  // bf16 buffers in dead f32 regions (h1 dead after relu_l2norm, p1 after segmax1)
  ushort_t* ob  = (ushort_t*)(ws + WS_H1);   // 6144x128 bf16
  ushort_t* xt  = (ushort_t*)(ws + WS_P1);   // 128x6144 bf16

  float* outp = (float*)d_out;
  const dim3 blk(256);

  // zero-init accumulators (ws is poisoned 0xAA before every call)
  hipMemsetAsync(deg, 0, 4096 * sizeof(int), stream);
  hipMemsetAsync(neigh, 0, 786432 * sizeof(float), stream);
  hipMemsetAsync(rowsum, 0, (6144 + 8) * sizeof(float), stream);  // rowsum + scal

  // CSR bucket-by-dst
  count_k<<<(E + 255) / 256, blk, 0, stream>>>(dst, deg, E);
  scan_k<<<1, 1024, 0, stream>>>(deg, rowptr, cursor);
  fill_k<<<(E + 255) / 256, blk, 0, stream>>>(src, dst, cursor, eidx, E);

  // layer 0
  gemm_nt<<<dim3(4, 64), blk, 0, stream>>>(feat, 256, W_pool0, 256,
                                           nullptr, 0, nullptr, 0,
                                           b_pool0, p0, 256, 256, 1);
  segmax_k<<<4096, 256, 0, stream>>>(p0, rowptr, eidx, hn0, 256);
  gemm_nt<<<dim3(2, 64), blk, 0, stream>>>(feat, 256, W_self0, 256,
                                           hn0, 256, W_neigh0, 256,
                                           b0, h1, 128, 256, 0);
  relu_l2norm_k<<<4096, 128, 0, stream>>>(h1, h1n);

  // layer 1
  gemm_nt<<<dim3(2, 64), blk, 0, stream>>>(h1n, 128, W_pool1, 128,
                                           nullptr, 0, nullptr, 0,
                                           b_pool1, p1, 128, 128, 1);
  segmax_k<<<4096, 128, 0, stream>>>(p1, rowptr, eidx, hn1, 128);
  gemm_nt<<<dim3(2, 64), blk, 0, stream>>>(h1n, 128, W_self1, 128,
                                           hn1, 128, W_neigh1, 128,
                                           b1, h2, 128, 128, 0);

  // SMOTE
  gemm_nt<<<dim3(16, 16), blk, 0, stream>>>(h2, 128, h2, 128,
                                            nullptr, 0, nullptr, 0,
                                            nullptr, dots, 1024, 128, 0);
  sqn_k<<<1024, 128, 0, stream>>>(h2, sqn);
  argmin_k<<<1024, 256, 0, stream>>>(dots, sqn, nn);
  build_x_k<<<6144, 128, 0, stream>>>(h2, nn, gaps, x);

  // decoder + bf16 conversions + fused adjacency pass
  gemm_nt<<<dim3(2, 96), blk, 0, stream>>>(x, 128, de_w, 128,
                                           nullptr, 0, nullptr, 0,
                                           nullptr, outm, 128, 128, 0);
  conv_ob_k<<<3072, blk, 0, stream>>>(outm, ob, 786432);
  conv_xt_k<<<dim3(96, 2), blk, 0, stream>>>(x, xt);
  fused_mfma<<<dim3(96, 8), blk, 0, stream>>>(ob, xt, adj, neigh, rowsum, scal, 12);
  neigh_div_k<<<6144, 128, 0, stream>>>(neigh, rowsum);

  // classifier
  gemm_nt<<<dim3(2, 96), blk, 0, stream>>>(x, 128, W_conv, 256,
                                           neigh, 128, W_conv + 128, 256,
                                           nullptr, hc, 128, 128, 0);
  logits_k<<<6144, 128, 0, stream>>>(hc, W_clf, b_clf, outp);
  y_k<<<24, blk, 0, stream>>>(labels, outp + 12288);
  loss_fin_k<<<1, 1, 0, stream>>>(scal, outp + 18432);

  (void)n_in; (void)out_size; (void)ws_size; (void)in_sizes;
}